// Round 1
// baseline (71.661 us; speedup 1.0000x reference)
//
#include <hip/hip_runtime.h>
#include <cstdint>
#include <cstddef>
#include <utility>

// ---------------------------------------------------------------------------
// out[8192,32] = x + P(x)[8192,6545] @ W[6545,32]
// P computed on the fly from compile-time monomial triples (no dynamic index).
// GEMM via v_mfma_f32_32x32x16_f16 (N=32 in one tile), fp32 accumulate.
// K padded 6545 -> 6656 = 16 chunks * 416 (26 MFMA steps of K=16).
// Grid: 256 M-tiles * 4 chunk-groups = 1024 blocks * 256 thr; wave w of a
// block handles chunk (cgroup*4 + w). Block LDS-reduces 4 partials, then
// atomicAdd fp32 into out (pre-initialized with x by init kernel).
// ---------------------------------------------------------------------------

#define NF 32
#define NPOLY 6545
#define KPAD 6656
#define CHUNK_K 416
#define STEPS 26   // 416 / 16

typedef _Float16 f16x8 __attribute__((ext_vector_type(8)));
typedef float f32x16 __attribute__((ext_vector_type(16)));

struct Tbl { uint32_t v[KPAD]; };

// entry: (cnt<<18)|(a<<12)|(b<<6)|c ; cnt=0 -> 1.0, 7 -> 0.0 (pad)
constexpr Tbl build_tbl() {
    Tbl t{};
    int k = 0;
    t.v[k++] = (0u << 18);                                   // constant 1
    for (int f = 0; f < NF; ++f)                             // degree 1
        t.v[k++] = (1u << 18) | (uint32_t(f) << 12);
    for (int f = 0; f < NF; ++f)                             // degree 2: x_f*x_m, m<=f
        for (int m = 0; m <= f; ++m)
            t.v[k++] = (2u << 18) | (uint32_t(f) << 12) | (uint32_t(m) << 6);
    for (int f = 0; f < NF; ++f) {                           // degree 3: x_f*d2[m]
        int cnt = (f + 1) * (f + 2) / 2;
        int g = 0, h = 0;
        for (int m = 0; m < cnt; ++m) {
            t.v[k++] = (3u << 18) | (uint32_t(f) << 12) | (uint32_t(g) << 6) | uint32_t(h);
            ++h;
            if (h > g) { ++g; h = 0; }
        }
    }
    while (k < KPAD) t.v[k++] = (7u << 18);                  // zero pad
    return t;
}

constexpr Tbl TBL = build_tbl();

template<int K>
__device__ __forceinline__ float mono(const float (&xr)[NF]) {
    constexpr uint32_t e = TBL.v[K];
    constexpr int cnt = int(e >> 18);
    constexpr int a = int((e >> 12) & 63);
    constexpr int b = int((e >> 6) & 63);
    constexpr int c = int(e & 63);
    if constexpr (cnt == 0) return 1.0f;
    else if constexpr (cnt == 1) return xr[a];
    else if constexpr (cnt == 2) return xr[a] * xr[b];
    else if constexpr (cnt == 3) return (xr[a] * xr[b]) * xr[c];  // CSE x_f*x_g across h-sweep
    else return 0.0f;
}

// A-fragment for v_mfma_f32_32x32x16_f16: lane holds A[m=lane&31][k=(lane>>5)*8+j].
// Both k-halves computed statically, selected by hsel (lane>>5) via cndmask.
template<int K0, int... Js>
__device__ __forceinline__ f16x8 gen_frag(const float (&xr)[NF], int hsel,
                                          std::integer_sequence<int, Js...>) {
    float lo[8] = { mono<K0 + Js>(xr)... };
    float hi[8] = { mono<K0 + 8 + Js>(xr)... };
    f16x8 r;
#pragma unroll
    for (int j = 0; j < 8; ++j)
        r[j] = (_Float16)(hsel ? hi[j] : lo[j]);
    return r;
}

template<int CB, int T>
__device__ __forceinline__ void step_one(const float (&xr)[NF], int hsel, int n,
                                         const _Float16* __restrict__ Wh,
                                         f32x16& acc) {
    constexpr int K0 = CB + T * 16;
    f16x8 a = gen_frag<K0>(xr, hsel, std::make_integer_sequence<int, 8>{});
    constexpr int TG = K0 >> 4;
    // Wh layout: [t][half][n][j], 8 f16 contiguous per (t,half,n)
    const f16x8* bp = (const f16x8*)(Wh + ((((TG * 2 + hsel) * 32) + n) << 3));
    f16x8 b = *bp;
    acc = __builtin_amdgcn_mfma_f32_32x32x16_f16(a, b, acc, 0, 0, 0);
}

template<int CB, int... Ts>
__device__ __forceinline__ void chunk_impl(std::integer_sequence<int, Ts...>,
                                           const float (&xr)[NF], int hsel, int n,
                                           const _Float16* __restrict__ Wh,
                                           f32x16& acc) {
    (step_one<CB, Ts>(xr, hsel, n, Wh, acc), ...);
}

template<int CB>
__device__ __forceinline__ void do_chunk(const float (&xr)[NF], int hsel, int n,
                                         const _Float16* __restrict__ Wh,
                                         f32x16& acc) {
    chunk_impl<CB>(std::make_integer_sequence<int, STEPS>{}, xr, hsel, n, Wh, acc);
}

__global__ void init_out(const float4* __restrict__ x, float4* __restrict__ out) {
    int id = blockIdx.x * 256 + threadIdx.x;   // 65536 float4 = 262144 floats
    out[id] = x[id];
}

__global__ void prep_w(const float* __restrict__ W, _Float16* __restrict__ Wh) {
    int id = blockIdx.x * 256 + threadIdx.x;   // 0 .. 212991  (6656*32)
    int n = id & 31;
    int k = id >> 5;                           // 0 .. 6655
    int t = k >> 4, kk = k & 15;
    int h = kk >> 3, j = kk & 7;
    float v = (k < NPOLY) ? W[k * 32 + n] : 0.0f;
    Wh[(((t * 2 + h) * 32 + n) << 3) + j] = (_Float16)v;
}

__global__ __launch_bounds__(256) void gemm(const float* __restrict__ x,
                                            const _Float16* __restrict__ Wh,
                                            float* __restrict__ out) {
    const int tid = threadIdx.x;
    const int wave = tid >> 6;
    const int lane = tid & 63;
    const int hsel = lane >> 5;
    const int m_local = lane & 31;
    const int mtile = blockIdx.x >> 2;
    const int cgroup = blockIdx.x & 3;
    const int chunk = cgroup * 4 + wave;

    // load this lane's row of x into registers (static-index array)
    const int row = mtile * 32 + m_local;
    float xr[NF];
    const float4* xp = (const float4*)(x + (size_t)row * NF);
#pragma unroll
    for (int i = 0; i < 8; ++i) {
        float4 v = xp[i];
        xr[4 * i + 0] = v.x; xr[4 * i + 1] = v.y;
        xr[4 * i + 2] = v.z; xr[4 * i + 3] = v.w;
    }

    f32x16 acc;
#pragma unroll
    for (int i = 0; i < 16; ++i) acc[i] = 0.0f;

    switch (chunk) {
        case  0: do_chunk< 0 * CHUNK_K>(xr, hsel, m_local, Wh, acc); break;
        case  1: do_chunk< 1 * CHUNK_K>(xr, hsel, m_local, Wh, acc); break;
        case  2: do_chunk< 2 * CHUNK_K>(xr, hsel, m_local, Wh, acc); break;
        case  3: do_chunk< 3 * CHUNK_K>(xr, hsel, m_local, Wh, acc); break;
        case  4: do_chunk< 4 * CHUNK_K>(xr, hsel, m_local, Wh, acc); break;
        case  5: do_chunk< 5 * CHUNK_K>(xr, hsel, m_local, Wh, acc); break;
        case  6: do_chunk< 6 * CHUNK_K>(xr, hsel, m_local, Wh, acc); break;
        case  7: do_chunk< 7 * CHUNK_K>(xr, hsel, m_local, Wh, acc); break;
        case  8: do_chunk< 8 * CHUNK_K>(xr, hsel, m_local, Wh, acc); break;
        case  9: do_chunk< 9 * CHUNK_K>(xr, hsel, m_local, Wh, acc); break;
        case 10: do_chunk<10 * CHUNK_K>(xr, hsel, m_local, Wh, acc); break;
        case 11: do_chunk<11 * CHUNK_K>(xr, hsel, m_local, Wh, acc); break;
        case 12: do_chunk<12 * CHUNK_K>(xr, hsel, m_local, Wh, acc); break;
        case 13: do_chunk<13 * CHUNK_K>(xr, hsel, m_local, Wh, acc); break;
        case 14: do_chunk<14 * CHUNK_K>(xr, hsel, m_local, Wh, acc); break;
        case 15: do_chunk<15 * CHUNK_K>(xr, hsel, m_local, Wh, acc); break;
        default: break;
    }

    // C/D layout (32x32): col = lane&31, row = (reg&3) + 8*(reg>>2) + 4*(lane>>5)
    __shared__ float red[4][32][32];
#pragma unroll
    for (int r = 0; r < 16; ++r) {
        int rr = (r & 3) + 8 * (r >> 2) + 4 * hsel;
        red[wave][rr][m_local] = acc[r];
    }
    __syncthreads();

#pragma unroll
    for (int i = 0; i < 4; ++i) {
        int e = tid + i * 256;          // 0..1023 over the 32x32 tile
        int rr = e >> 5, cc = e & 31;
        float s = red[0][rr][cc] + red[1][rr][cc] + red[2][rr][cc] + red[3][rr][cc];
        atomicAdd(out + ((size_t)(mtile * 32 + rr) * 32 + cc), s);
    }
}

extern "C" void kernel_launch(void* const* d_in, const int* in_sizes, int n_in,
                              void* d_out, int out_size, void* d_ws, size_t ws_size,
                              hipStream_t stream) {
    (void)in_sizes; (void)n_in; (void)out_size; (void)ws_size;
    const float* x = (const float*)d_in[0];   // [8192,32]
    const float* W = (const float*)d_in[1];   // [6545,32]
    float* out = (float*)d_out;               // [8192,32]
    _Float16* Wh = (_Float16*)d_ws;           // needs 6656*32*2 = 425984 B

    init_out<<<256, 256, 0, stream>>>((const float4*)x, (float4*)out);
    prep_w<<<832, 256, 0, stream>>>(W, Wh);
    gemm<<<1024, 256, 0, stream>>>(x, Wh, out);
}